// Round 3
// baseline (546.829 us; speedup 1.0000x reference)
//
#include <hip/hip_runtime.h>
#include <math.h>

// B=256, S2=32768, HID=512, HEADS=1024
// c1 = tanh(in@W_c1^T+b_c1); cx = sigmoid(c1@W_c2^T); x1 = kwta(in@W1^T+b1, cx*1024)
// x2 = kwta(x1@W2^T+b2, cx*512); x3 = kwta(x2@W3^T+b3, cx*1024); out = x3@W4^T
//
// All GEMMs: split-bf16 3-term MFMA (hi*hi + hi*lo + lo*hi); dropped lo*lo is
// ~2^-18 relative. Big GEMM fuses W_c1|W1 (N=1536, K=32768), 32x32x16 MFMA.
// R3 polish: big GEMM step reordered to the proven template order —
// frag ds_reads FIRST (regs), then glds/stageW (so the compiler never sees a
// ds_read after an aliasing global_load_lds and cannot insert a vmcnt drain
// before the MFMA region). One counted vmcnt(4) per step; W never drained.

typedef __attribute__((ext_vector_type(8))) short bf16x8;
typedef __attribute__((ext_vector_type(4))) float f32x4;
typedef __attribute__((ext_vector_type(16))) float f32x16;

// Pack two fp32 into bf16-hi pair and bf16-lo (residual) pair via v_perm.
__device__ __forceinline__ void split2(float f0, float f1, unsigned& hi, unsigned& lo) {
  unsigned u0 = __float_as_uint(f0), u1 = __float_as_uint(f1);
  hi = __builtin_amdgcn_perm(u1, u0, 0x07060302u);  // (u1_hi16<<16)|u0_hi16
  float r0 = f0 - __uint_as_float(u0 & 0xffff0000u);
  float r1 = f1 - __uint_as_float(u1 & 0xffff0000u);
  lo = __builtin_amdgcn_perm(__float_as_uint(r1), __float_as_uint(r0), 0x07060302u);
}

#define GLDS16(g, l)                                                   \
  __builtin_amdgcn_global_load_lds(                                    \
      (const __attribute__((address_space(1))) unsigned int*)(g),      \
      (__attribute__((address_space(3))) unsigned int*)(l), 16, 0, 0)

// ---------------------------------------------------------------------------
// Pre-split A [256,32768] into blocked bf16 hi/lo: Ahg[k8][row][8] shorts.
// LDS-transpose tiles of 64 rows x 128 k-floats; both phases coalesced.
// ---------------------------------------------------------------------------
__global__ __launch_bounds__(256, 4) void presplit_a(
    const float* __restrict__ A, short* __restrict__ Ahg, short* __restrict__ Alg) {
  __shared__ short sh[8192], sl[8192];  // [64 rows][16 slots][8 shorts]
  const int t = threadIdx.x;
  const int r0 = (blockIdx.x & 3) * 64;
  const int k0 = (blockIdx.x >> 2) * 128;  // in floats
#pragma unroll
  for (int i = 0; i < 8; ++i) {
    const int row = i * 8 + (t >> 5);
    const int kf = (t & 31) * 4;
    const float4 v = *(const float4*)(A + (size_t)(r0 + row) * 32768 + k0 + kf);
    unsigned h0, l0, h1, l1;
    split2(v.x, v.y, h0, l0); split2(v.z, v.w, h1, l1);
    const int slot = (kf >> 3) ^ (row & 15);
    const int part = kf & 7;  // 0 or 4
    *(uint2*)&sh[(row * 16 + slot) * 8 + part] = (uint2){h0, h1};
    *(uint2*)&sl[(row * 16 + slot) * 8 + part] = (uint2){l0, l1};
  }
  __syncthreads();
#pragma unroll
  for (int i = 0; i < 4; ++i) {
    const int row = t & 63;
    const int k8 = (t >> 6) * 4 + i;
    const int slot = k8 ^ (row & 15);
    const size_t dst = ((size_t)(k0 / 8 + k8) * 256 + r0 + row) * 8;
    *(uint4*)(Ahg + dst) = *(const uint4*)&sh[(row * 16 + slot) * 8];
    *(uint4*)(Alg + dst) = *(const uint4*)&sl[(row * 16 + slot) * 8];
  }
}

// ---------------------------------------------------------------------------
// Pre-split W2 (512x1024), W3 (1024x512), W4 (1024x1024) into bf16 hi/lo.
// ---------------------------------------------------------------------------
__global__ __launch_bounds__(256) void presplit_w(
    const float* __restrict__ W2, const float* __restrict__ W3,
    const float* __restrict__ W4, short* __restrict__ W2h, short* __restrict__ W2l,
    short* __restrict__ W3h, short* __restrict__ W3l,
    short* __restrict__ W4h, short* __restrict__ W4l) {
  const int e = (blockIdx.x * 256 + threadIdx.x) * 8;
  const float* src; short *dh, *dl; int off;
  if (e < 524288) { src = W2; dh = W2h; dl = W2l; off = e; }
  else if (e < 1048576) { src = W3; dh = W3h; dl = W3l; off = e - 524288; }
  else { src = W4; dh = W4h; dl = W4l; off = e - 1048576; }
  const float4 a = *(const float4*)(src + off);
  const float4 b = *(const float4*)(src + off + 4);
  unsigned h0, l0, h1, l1, h2, l2, h3, l3;
  split2(a.x, a.y, h0, l0); split2(a.z, a.w, h1, l1);
  split2(b.x, b.y, h2, l2); split2(b.z, b.w, h3, l3);
  *(uint4*)(dh + off) = (uint4){h0, h1, h2, h3};
  *(uint4*)(dl + off) = (uint4){l0, l1, l2, l3};
}

// ---------------------------------------------------------------------------
// Big fused GEMM: P[z] = A[256,32768] @ concat(W_c1,W1)[1536,32768]^T chunk z.
// BM=128, BN=128, BK=32; 4 waves 2x2; wave tile 64x64 = 2x2 of 32x32x16.
// Step order (template-conformant: ds_read BEFORE glds, counted vmcnt only):
//   frag ds_reads x16 -> regs | lgkmcnt(0) | barrier |
//   glds A(s+1) | stageW(s+1) (rw, vmcnt<=4) | issueW(s+2) | MFMA x24 (regs) |
//   vmcnt(4)+lgkmcnt(0) | barrier
// A glds get a full MFMA wall of cover; W loads never drained below 4.
// ---------------------------------------------------------------------------
__global__ __launch_bounds__(256, 3) void big_gemm5(
    const short* __restrict__ Ahg, const short* __restrict__ Alg,
    const float* __restrict__ Wc1, const float* __restrict__ W1,
    float* __restrict__ P, int stepsPerZ) {
  __shared__ short sAh[2][4096], sAl[2][4096], sWh[4096], sWl[4096];
  const int tid = threadIdx.x;
  // XCD-aware decode (round-robin id%8): XCD x owns whole z-chunks; the 24
  // blocks of one z run on one XCD so A z-chunk + W panels stay L2-hot.
  const int g = blockIdx.x;
  const int x = g & 7, t = g >> 3;
  const int z = x + 8 * (t / 24);
  const int inner = t % 24;
  const int n0 = (inner % 12) * 128;
  const int m0 = (inner / 12) * 128;
  const float* Wp = (n0 < 512) ? (Wc1 + (size_t)n0 * 32768)
                               : (W1 + (size_t)(n0 - 512) * 32768);
  const int lane = tid & 63, wv = tid >> 6;
  const int wm = wv & 1, wn = wv >> 1;
  const int l31 = lane & 31, khalf = lane >> 5;
  const int srow = tid >> 1, shalf = tid & 1;  // W staging: 2 threads/row, 16 floats

  f32x16 acc[2][2];
#pragma unroll
  for (int i = 0; i < 2; ++i)
#pragma unroll
    for (int j = 0; j < 2; ++j)
#pragma unroll
      for (int r = 0; r < 16; ++r) acc[i][j][r] = 0.f;

  // A DMA assignment: wave wv covers (k8-slab = wv>>1 and +2, row-half = wv&1).
  const int aslab = wv >> 1, ahalf = wv & 1;
  const int arowg = m0 + ahalf * 64 + lane;            // per-lane global row
  const int aoff0 = (aslab * 128 + ahalf * 64) * 8;    // wave-uniform LDS offs
  const int aoff1 = ((aslab + 2) * 128 + ahalf * 64) * 8;

  const float* Wq = Wp + (size_t)srow * 32768 + shalf * 16;

  float4 rw[4];  // W prefetch registers
  auto issueW = [&](int kkx) {
#pragma unroll
    for (int c = 0; c < 4; ++c) rw[c] = *(const float4*)(Wq + kkx + c * 4);
  };
  auto issueA = [&](int buf, int kkx) {
    const size_t k8b = (size_t)(kkx >> 3);
    GLDS16(Ahg + ((k8b + aslab) * 256 + arowg) * 8, &sAh[buf][aoff0]);
    GLDS16(Alg + ((k8b + aslab) * 256 + arowg) * 8, &sAl[buf][aoff0]);
    GLDS16(Ahg + ((k8b + aslab + 2) * 256 + arowg) * 8, &sAh[buf][aoff1]);
    GLDS16(Alg + ((k8b + aslab + 2) * 256 + arowg) * 8, &sAl[buf][aoff1]);
  };
  auto stageW = [&]() {
    unsigned h0, l0, h1, l1, h2, l2, h3, l3;
    split2(rw[0].x, rw[0].y, h0, l0); split2(rw[0].z, rw[0].w, h1, l1);
    split2(rw[1].x, rw[1].y, h2, l2); split2(rw[1].z, rw[1].w, h3, l3);
    *(uint4*)&sWh[(2 * shalf * 128 + srow) * 8] = (uint4){h0, h1, h2, h3};
    *(uint4*)&sWl[(2 * shalf * 128 + srow) * 8] = (uint4){l0, l1, l2, l3};
    split2(rw[2].x, rw[2].y, h0, l0); split2(rw[2].z, rw[2].w, h1, l1);
    split2(rw[3].x, rw[3].y, h2, l2); split2(rw[3].z, rw[3].w, h3, l3);
    *(uint4*)&sWh[((2 * shalf + 1) * 128 + srow) * 8] = (uint4){h0, h1, h2, h3};
    *(uint4*)&sWl[((2 * shalf + 1) * 128 + srow) * 8] = (uint4){l0, l1, l2, l3};
  };

  const int kkBase = z * stepsPerZ * 32;
  int kk = kkBase;
  // Prologue: W(0)->rw first, then A(0) glds; stage W(0); start W(1);
  // counted drain so only A is waited (W(1) keeps flying).
  issueW(kk);
  issueA(0, kk);
  stageW();  // auto vmcnt(4): waits W(0), A glds still in flight
  issueW(kk + 32);
  asm volatile("s_waitcnt vmcnt(4) lgkmcnt(0)" ::: "memory");  // A(0) landed
  __builtin_amdgcn_s_barrier();
  __builtin_amdgcn_sched_barrier(0);

  int cur = 0;
  for (int s = 0; s < stepsPerZ; ++s, kk += 32) {
    // 1. ALL fragments of this step -> regs (ds_read BEFORE any glds issue)
    bf16x8 ah[2][2], al[2][2], wh[2][2], wl[2][2];
#pragma unroll
    for (int ks = 0; ks < 2; ++ks)
#pragma unroll
      for (int i = 0; i < 2; ++i) {
        const int offA = ((ks * 2 + khalf) * 128 + wm * 64 + i * 32 + l31) * 8;
        ah[ks][i] = *(const bf16x8*)&sAh[cur][offA];
        al[ks][i] = *(const bf16x8*)&sAl[cur][offA];
        const int offW = ((ks * 2 + khalf) * 128 + wn * 64 + i * 32 + l31) * 8;
        wh[ks][i] = *(const bf16x8*)&sWh[offW];
        wl[ks][i] = *(const bf16x8*)&sWl[offW];
      }
    asm volatile("s_waitcnt lgkmcnt(0)" ::: "memory");
    __builtin_amdgcn_sched_barrier(0);
    __builtin_amdgcn_s_barrier();  // sA[cur] + sW now dead for all waves
    __builtin_amdgcn_sched_barrier(0);

    const bool hasNext = (s + 1 < stepsPerZ);
    if (hasNext) {
      issueA(cur ^ 1, kk + 32);                        // glds, lands under MFMA
      stageW();                                        // W(s+1)->sW, vmcnt<=4
      issueW((s + 2 < stepsPerZ) ? kk + 64 : kkBase);  // W(s+2) (or dummy)
    }
    __builtin_amdgcn_s_setprio(1);
#pragma unroll
    for (int ks = 0; ks < 2; ++ks)
#pragma unroll
      for (int i = 0; i < 2; ++i)
#pragma unroll
        for (int j = 0; j < 2; ++j) {
          acc[i][j] = __builtin_amdgcn_mfma_f32_32x32x16_bf16(ah[ks][i], wh[ks][j], acc[i][j], 0, 0, 0);
          acc[i][j] = __builtin_amdgcn_mfma_f32_32x32x16_bf16(ah[ks][i], wl[ks][j], acc[i][j], 0, 0, 0);
          acc[i][j] = __builtin_amdgcn_mfma_f32_32x32x16_bf16(al[ks][i], wh[ks][j], acc[i][j], 0, 0, 0);
        }
    __builtin_amdgcn_s_setprio(0);
    if (hasNext) {
      __builtin_amdgcn_sched_barrier(0);
      asm volatile("s_waitcnt vmcnt(4) lgkmcnt(0)" ::: "memory");  // A(s+1) in
      __builtin_amdgcn_s_barrier();
      __builtin_amdgcn_sched_barrier(0);
      cur ^= 1;
    }
  }
  // C/D layout (32x32): col = lane&31, row = (r&3) + 8*(r>>2) + 4*(lane>>5)
#pragma unroll
  for (int i = 0; i < 2; ++i)
#pragma unroll
    for (int j = 0; j < 2; ++j)
#pragma unroll
      for (int r = 0; r < 16; ++r) {
        const int m = m0 + wm * 64 + i * 32 + (r & 3) + 8 * (r >> 2) + 4 * khalf;
        const int n = n0 + wn * 64 + j * 32 + l31;
        P[((size_t)z * 256 + m) * 1536 + n] = acc[i][j][r];
      }
}

// ---------------------------------------------------------------------------
// cx = sigmoid(sum_n tanh(c1_preact)*Wc2). Fuses split-K reduce of c1 columns.
// ---------------------------------------------------------------------------
__global__ __launch_bounds__(256) void cx_fused(
    const float* __restrict__ P, const float* __restrict__ b_c1,
    const float* __restrict__ Wc2, float* __restrict__ cx, int S) {
  const int r = blockIdx.x, t = threadIdx.x;
  __shared__ float red[4];
  float total = 0.f;
#pragma unroll
  for (int half = 0; half < 2; ++half) {
    const int c = t + half * 256;
    float s = 0.f;
    for (int z = 0; z < S; ++z) s += P[((size_t)z * 256 + r) * 1536 + c];
    total += tanhf(s + b_c1[c]) * Wc2[c];
  }
#pragma unroll
  for (int off = 32; off; off >>= 1) total += __shfl_down(total, off, 64);
  if ((t & 63) == 0) red[t >> 6] = total;
  __syncthreads();
  if (t == 0) {
    const float s = red[0] + red[1] + red[2] + red[3];
    cx[r] = 1.f / (1.f + expf(-s));
  }
}

// ---------------------------------------------------------------------------
// Fused: split-K reduce + bias -> kwta (exact stable-argsort ties) -> emit
// hi/lo bf16 for the next GEMM. One block per row, n threads.
// ---------------------------------------------------------------------------
__global__ void kwta_fused(
    const float* __restrict__ P, int ldP, int colOff, int S,
    const float* __restrict__ bias, const float* __restrict__ cx,
    short* __restrict__ xh, short* __restrict__ xl, int n) {
  extern __shared__ float sdata[];
  const int row = blockIdx.x, j = threadIdx.x;
  float v = 0.f;
  for (int z = 0; z < S; ++z) v += P[((size_t)z * 256 + row) * ldP + colOff + j];
  v += bias[j];
  sdata[j] = v;
  __syncthreads();
  const int k = (int)(cx[row] * (float)n);  // trunc, matches .astype(int32)
  int cnt = 0;
  const float4* s4 = (const float4*)sdata;
  for (int i4 = 0; i4 < (n >> 2); ++i4) {
    const float4 s = s4[i4];
    const int b = i4 << 2;
    cnt += (s.x > v || (s.x == v && b < j));
    cnt += (s.y > v || (s.y == v && b + 1 < j));
    cnt += (s.z > v || (s.z == v && b + 2 < j));
    cnt += (s.w > v || (s.w == v && b + 3 < j));
  }
  const float o = (cnt < k) ? v : 0.f;
  const unsigned u = __float_as_uint(o);
  xh[(size_t)row * n + j] = (short)(unsigned short)(u >> 16);
  const float rr = o - __uint_as_float(u & 0xffff0000u);
  xl[(size_t)row * n + j] = (short)(unsigned short)(__float_as_uint(rr) >> 16);
}

// ---------------------------------------------------------------------------
// Small GEMM, pre-split bf16 operands, 3-term 16x16x32 MFMA (R2-verified
// layout). Block 64x64, 4 waves (wave = 16 rows x 64 cols), split-K partials.
// ---------------------------------------------------------------------------
__global__ __launch_bounds__(256, 4) void gemm_sk(
    const short* __restrict__ Xh, const short* __restrict__ Xl,
    const short* __restrict__ Wh, const short* __restrict__ Wl,
    float* __restrict__ P, int N, int K, int stepsPerZ) {
  __shared__ short sXh[64 * 40], sXl[64 * 40], sWh[64 * 40], sWl[64 * 40];
  const int tid = threadIdx.x;
  const int n0 = blockIdx.x * 64, m0 = blockIdx.y * 64, z = blockIdx.z;
  const int lane = tid & 63, w = tid >> 6;
  const int l15 = lane & 15, q = lane >> 4;
  const int srow = tid >> 2, schunk = tid & 3;

  f32x4 acc[4];
#pragma unroll
  for (int j = 0; j < 4; ++j) acc[j] = (f32x4){0.f, 0.f, 0.f, 0.f};

  const short* pXh = Xh + (size_t)(m0 + srow) * K + schunk * 8;
  const short* pXl = Xl + (size_t)(m0 + srow) * K + schunk * 8;
  const short* pWh = Wh + (size_t)(n0 + srow) * K + schunk * 8;
  const short* pWl = Wl + (size_t)(n0 + srow) * K + schunk * 8;
  short* dXh = &sXh[srow * 40 + schunk * 8];
  short* dXl = &sXl[srow * 40 + schunk * 8];
  short* dWh = &sWh[srow * 40 + schunk * 8];
  short* dWl = &sWl[srow * 40 + schunk * 8];

  int kk = z * stepsPerZ * 32;
  for (int s = 0; s < stepsPerZ; ++s, kk += 32) {
    *(bf16x8*)dXh = *(const bf16x8*)(pXh + kk);
    *(bf16x8*)dXl = *(const bf16x8*)(pXl + kk);
    *(bf16x8*)dWh = *(const bf16x8*)(pWh + kk);
    *(bf16x8*)dWl = *(const bf16x8*)(pWl + kk);
    __syncthreads();
    const int aoff = (w * 16 + l15) * 40 + q * 8;
    const bf16x8 ah = *(const bf16x8*)&sXh[aoff];
    const bf16x8 al = *(const bf16x8*)&sXl[aoff];
#pragma unroll
    for (int j = 0; j < 4; ++j) {
      const int woff = (j * 16 + l15) * 40 + q * 8;
      const bf16x8 whf = *(const bf16x8*)&sWh[woff];
      const bf16x8 wlf = *(const bf16x8*)&sWl[woff];
      acc[j] = __builtin_amdgcn_mfma_f32_16x16x32_bf16(ah, whf, acc[j], 0, 0, 0);
      acc[j] = __builtin_amdgcn_mfma_f32_16x16x32_bf16(ah, wlf, acc[j], 0, 0, 0);
      acc[j] = __builtin_amdgcn_mfma_f32_16x16x32_bf16(al, whf, acc[j], 0, 0, 0);
    }
    __syncthreads();
  }
  // C/D (16x16): col = lane&15, row = (lane>>4)*4 + r
#pragma unroll
  for (int j = 0; j < 4; ++j)
#pragma unroll
    for (int r = 0; r < 4; ++r) {
      const int m = m0 + w * 16 + q * 4 + r;
      const int n = n0 + j * 16 + l15;
      P[((size_t)z * 256 + m) * N + n] = acc[j][r];
    }
}

__global__ __launch_bounds__(256) void reduce_out(
    const float* __restrict__ P, float* __restrict__ out, int S) {
  const int idx = blockIdx.x * 256 + threadIdx.x;
  float s = 0.f;
  for (int z = 0; z < S; ++z) s += P[(size_t)z * 262144 + idx];
  out[idx] = s;
}

extern "C" void kernel_launch(void* const* d_in, const int* in_sizes, int n_in,
                              void* d_out, int out_size, void* d_ws, size_t ws_size,
                              hipStream_t stream) {
  const float* input = (const float*)d_in[0];
  const float* W_c1  = (const float*)d_in[1];
  const float* b_c1  = (const float*)d_in[2];
  const float* W_c2  = (const float*)d_in[3];
  const float* W1    = (const float*)d_in[4];
  const float* b1    = (const float*)d_in[5];
  const float* W2    = (const float*)d_in[6];
  const float* b2    = (const float*)d_in[7];
  const float* W3    = (const float*)d_in[8];
  const float* b3    = (const float*)d_in[9];
  const float* W4    = (const float*)d_in[10];
  float* out = (float*)d_out;

  char* wsb = (char*)d_ws;
  size_t off = 0;
  auto alloc = [&](size_t bytes) {
    char* p = wsb + off;
    off += (bytes + 255) & ~(size_t)255;
    return p;
  };
  float* cx  = (float*)alloc(1024);
  short* x1h = (short*)alloc(524288);  short* x1l = (short*)alloc(524288);
  short* x2h = (short*)alloc(262144);  short* x2l = (short*)alloc(262144);
  short* x3h = (short*)alloc(524288);  short* x3l = (short*)alloc(524288);
  short* W2h = (short*)alloc(1048576); short* W2l = (short*)alloc(1048576);
  short* W3h = (short*)alloc(1048576); short* W3l = (short*)alloc(1048576);
  short* W4h = (short*)alloc(2097152); short* W4l = (short*)alloc(2097152);
  short* Ahg = (short*)alloc(16777216); short* Alg = (short*)alloc(16777216);
  // Split-K partial buffer (big GEMM: S*256*1536 fp32; small GEMMs reuse <=4 MB)
  int S_big = 32;
  while (S_big > 8 && off + (size_t)S_big * 1572864ull > ws_size) S_big >>= 1;
  float* P = (float*)(wsb + off);
  const int stepsBig = 1024 / S_big;  // K-32 steps per z-chunk

  // 1. pre-split A (blocked layout for global_load_lds) + small weights
  presplit_a<<<1024, 256, 0, stream>>>(input, Ahg, Alg);
  presplit_w<<<1024, 256, 0, stream>>>(W2, W3, W4, W2h, W2l, W3h, W3l, W4h, W4l);
  // 2. big fused GEMM -> P  (1D grid, XCD-aware decode inside; 24 blocks/z)
  big_gemm5<<<24 * S_big, 256, 0, stream>>>(Ahg, Alg, W_c1, W1, P, stepsBig);
  // 3. cx (fuses c1 reduce + tanh + dot + sigmoid)
  cx_fused<<<256, 256, 0, stream>>>(P, b_c1, W_c2, cx, S_big);
  // 4. kwta x1 (reduce P cols 512..1536 + b1) -> x1h/x1l
  kwta_fused<<<256, 1024, 1024 * 4, stream>>>(P, 1536, 512, S_big, b1, cx, x1h, x1l, 1024);
  // 5. x2 = x1 @ W2^T : K=1024, N=512, S=8
  {
    dim3 g(8, 4, 8);
    gemm_sk<<<g, 256, 0, stream>>>(x1h, x1l, W2h, W2l, P, 512, 1024, 4);
  }
  // 6. kwta x2 (+b2) -> x2h/x2l
  kwta_fused<<<256, 512, 512 * 4, stream>>>(P, 512, 0, 8, b2, cx, x2h, x2l, 512);
  // 7. x3 = x2 @ W3^T : K=512, N=1024, S=4
  {
    dim3 g(16, 4, 4);
    gemm_sk<<<g, 256, 0, stream>>>(x2h, x2l, W3h, W3l, P, 1024, 512, 4);
  }
  // 8. kwta x3 (+b3) -> x3h/x3l
  kwta_fused<<<256, 1024, 1024 * 4, stream>>>(P, 1024, 0, 4, b3, cx, x3h, x3l, 1024);
  // 9. out = x3 @ W4^T : K=1024, N=1024, S=4
  {
    dim3 g(16, 4, 4);
    gemm_sk<<<g, 256, 0, stream>>>(x3h, x3l, W4h, W4l, P, 1024, 1024, 8);
  }
  // 10. final reduce
  reduce_out<<<1024, 256, 0, stream>>>(P, out, 4);
}

// Round 4
// 454.009 us; speedup vs baseline: 1.2044x; 1.2044x over previous
//
#include <hip/hip_runtime.h>
#include <math.h>

// B=256, S2=32768, HID=512, HEADS=1024
// c1 = tanh(in@W_c1^T+b_c1); cx = sigmoid(c1@W_c2^T); x1 = kwta(in@W1^T+b1, cx*1024)
// x2 = kwta(x1@W2^T+b2, cx*512); x3 = kwta(x2@W3^T+b3, cx*1024); out = x3@W4^T
//
// All GEMMs: split-bf16 3-term MFMA (hi*hi + hi*lo + lo*hi); dropped lo*lo is
// ~2^-18 relative. Big GEMM fuses W_c1|W1 (N=1536, K=32768), 32x32x16 MFMA.
// R4: big GEMM reverted to the empirically-best R1 loop (compiler-scheduled,
// 2 barriers; 118 us) + XCD-aware decode (FETCH halves). Tail overhaul:
// cx fused into kwta-x1; all z-reduce loops 4-way unrolled (ILP); small GEMMs
// split-K doubled (2 blocks/CU) + T14 reg-prefetch; presplits merged.

typedef __attribute__((ext_vector_type(8))) short bf16x8;
typedef __attribute__((ext_vector_type(4))) float f32x4;
typedef __attribute__((ext_vector_type(16))) float f32x16;

// Pack two fp32 into bf16-hi pair and bf16-lo (residual) pair via v_perm.
__device__ __forceinline__ void split2(float f0, float f1, unsigned& hi, unsigned& lo) {
  unsigned u0 = __float_as_uint(f0), u1 = __float_as_uint(f1);
  hi = __builtin_amdgcn_perm(u1, u0, 0x07060302u);  // (u1_hi16<<16)|u0_hi16
  float r0 = f0 - __uint_as_float(u0 & 0xffff0000u);
  float r1 = f1 - __uint_as_float(u1 & 0xffff0000u);
  lo = __builtin_amdgcn_perm(__float_as_uint(r1), __float_as_uint(r0), 0x07060302u);
}

#define GLDS16(g, l)                                                   \
  __builtin_amdgcn_global_load_lds(                                    \
      (const __attribute__((address_space(1))) unsigned int*)(g),      \
      (__attribute__((address_space(3))) unsigned int*)(l), 16, 0, 0)

// ---------------------------------------------------------------------------
// Merged pre-split. Blocks [0,1024): A [256,32768] -> blocked bf16 hi/lo
// Ahg[k8][row][8] via LDS-transpose tiles (both phases coalesced).
// Blocks [1024,2048): W2/W3/W4 row-major bf16 hi/lo.
// ---------------------------------------------------------------------------
__global__ __launch_bounds__(256, 4) void presplit_aw(
    const float* __restrict__ A, short* __restrict__ Ahg, short* __restrict__ Alg,
    const float* __restrict__ W2, const float* __restrict__ W3,
    const float* __restrict__ W4, short* __restrict__ W2h, short* __restrict__ W2l,
    short* __restrict__ W3h, short* __restrict__ W3l,
    short* __restrict__ W4h, short* __restrict__ W4l) {
  __shared__ short sh[8192], sl[8192];  // [64 rows][16 slots][8 shorts]
  const int t = threadIdx.x;
  if (blockIdx.x < 1024) {
    const int r0 = (blockIdx.x & 3) * 64;
    const int k0 = (blockIdx.x >> 2) * 128;  // in floats
#pragma unroll
    for (int i = 0; i < 8; ++i) {
      const int row = i * 8 + (t >> 5);
      const int kf = (t & 31) * 4;
      const float4 v = *(const float4*)(A + (size_t)(r0 + row) * 32768 + k0 + kf);
      unsigned h0, l0, h1, l1;
      split2(v.x, v.y, h0, l0); split2(v.z, v.w, h1, l1);
      const int slot = (kf >> 3) ^ (row & 15);
      const int part = kf & 7;  // 0 or 4
      *(uint2*)&sh[(row * 16 + slot) * 8 + part] = (uint2){h0, h1};
      *(uint2*)&sl[(row * 16 + slot) * 8 + part] = (uint2){l0, l1};
    }
    __syncthreads();
#pragma unroll
    for (int i = 0; i < 4; ++i) {
      const int row = t & 63;
      const int k8 = (t >> 6) * 4 + i;
      const int slot = k8 ^ (row & 15);
      const size_t dst = ((size_t)(k0 / 8 + k8) * 256 + r0 + row) * 8;
      *(uint4*)(Ahg + dst) = *(const uint4*)&sh[(row * 16 + slot) * 8];
      *(uint4*)(Alg + dst) = *(const uint4*)&sl[(row * 16 + slot) * 8];
    }
  } else {
    const int e = ((blockIdx.x - 1024) * 256 + t) * 8;
    const float* src; short *dh, *dl; int off;
    if (e < 524288) { src = W2; dh = W2h; dl = W2l; off = e; }
    else if (e < 1048576) { src = W3; dh = W3h; dl = W3l; off = e - 524288; }
    else { src = W4; dh = W4h; dl = W4l; off = e - 1048576; }
    const float4 a = *(const float4*)(src + off);
    const float4 b = *(const float4*)(src + off + 4);
    unsigned h0, l0, h1, l1, h2, l2, h3, l3;
    split2(a.x, a.y, h0, l0); split2(a.z, a.w, h1, l1);
    split2(b.x, b.y, h2, l2); split2(b.z, b.w, h3, l3);
    *(uint4*)(dh + off) = (uint4){h0, h1, h2, h3};
    *(uint4*)(dl + off) = (uint4){l0, l1, l2, l3};
  }
}

// ---------------------------------------------------------------------------
// Big fused GEMM: P[z] = A[256,32768] @ concat(W_c1,W1)[1536,32768]^T chunk z.
// BM=128, BN=128, BK=32; 4 waves 2x2; wave tile 64x64 = 2x2 of 32x32x16.
// R1-proven loop body (compiler-scheduled, 2 __syncthreads per step):
//   issueA(glds) | stageW (rw landed during prev MFMA) | barrier |
//   issueW(next) | frag ds_reads interleaved with MFMA x24 | barrier
// + XCD-aware 1D decode: XCD x owns whole z-chunks (24 blocks each), so the
// A z-chunk (1 MB) and W panels stay L2-resident (FETCH 331->156 MB).
// ---------------------------------------------------------------------------
__global__ __launch_bounds__(256, 3) void big_gemm6(
    const short* __restrict__ Ahg, const short* __restrict__ Alg,
    const float* __restrict__ Wc1, const float* __restrict__ W1,
    float* __restrict__ P, int stepsPerZ) {
  __shared__ short sAh[4096], sAl[4096], sWh[4096], sWl[4096];
  const int tid = threadIdx.x;
  const int g = blockIdx.x;
  const int x = g & 7, tb = g >> 3;
  const int z = x + 8 * (tb / 24);
  const int inner = tb % 24;
  const int n0 = (inner % 12) * 128;
  const int m0 = (inner / 12) * 128;
  const float* Wp = (n0 < 512) ? (Wc1 + (size_t)n0 * 32768)
                               : (W1 + (size_t)(n0 - 512) * 32768);
  const int lane = tid & 63, wv = tid >> 6;
  const int wm = wv & 1, wn = wv >> 1;
  const int l31 = lane & 31, khalf = lane >> 5;
  const int srow = tid >> 1, shalf = tid & 1;  // W staging: 2 threads/row, 16 floats

  f32x16 acc[2][2];
#pragma unroll
  for (int i = 0; i < 2; ++i)
#pragma unroll
    for (int j = 0; j < 2; ++j)
#pragma unroll
      for (int r = 0; r < 16; ++r) acc[i][j][r] = 0.f;

  // A DMA assignment: wave wv covers (k8-slab = wv>>1 and +2, row-half = wv&1).
  const int aslab = wv >> 1, ahalf = wv & 1;
  const int arowg = m0 + ahalf * 64 + lane;  // per-lane global row
  short* ldsAh0 = &sAh[(aslab * 128 + ahalf * 64) * 8];  // wave-uniform
  short* ldsAl0 = &sAl[(aslab * 128 + ahalf * 64) * 8];
  short* ldsAh1 = &sAh[((aslab + 2) * 128 + ahalf * 64) * 8];
  short* ldsAl1 = &sAl[((aslab + 2) * 128 + ahalf * 64) * 8];

  const float* Wq = Wp + (size_t)srow * 32768 + shalf * 16;

  float4 rw[4];  // W prefetch registers (consumed before re-issue)
  auto issueW = [&](int kkx) {
#pragma unroll
    for (int c = 0; c < 4; ++c) rw[c] = *(const float4*)(Wq + kkx + c * 4);
  };
  auto issueA = [&](int kkx) {
    const size_t k8b = (size_t)(kkx >> 3);
    GLDS16(Ahg + ((k8b + aslab) * 256 + arowg) * 8, ldsAh0);
    GLDS16(Alg + ((k8b + aslab) * 256 + arowg) * 8, ldsAl0);
    GLDS16(Ahg + ((k8b + aslab + 2) * 256 + arowg) * 8, ldsAh1);
    GLDS16(Alg + ((k8b + aslab + 2) * 256 + arowg) * 8, ldsAl1);
  };
  auto stageW = [&]() {
    unsigned h0, l0, h1, l1, h2, l2, h3, l3;
    split2(rw[0].x, rw[0].y, h0, l0); split2(rw[0].z, rw[0].w, h1, l1);
    split2(rw[1].x, rw[1].y, h2, l2); split2(rw[1].z, rw[1].w, h3, l3);
    *(uint4*)&sWh[(2 * shalf * 128 + srow) * 8] = (uint4){h0, h1, h2, h3};
    *(uint4*)&sWl[(2 * shalf * 128 + srow) * 8] = (uint4){l0, l1, l2, l3};
    split2(rw[2].x, rw[2].y, h0, l0); split2(rw[2].z, rw[2].w, h1, l1);
    split2(rw[3].x, rw[3].y, h2, l2); split2(rw[3].z, rw[3].w, h3, l3);
    *(uint4*)&sWh[((2 * shalf + 1) * 128 + srow) * 8] = (uint4){h0, h1, h2, h3};
    *(uint4*)&sWl[((2 * shalf + 1) * 128 + srow) * 8] = (uint4){l0, l1, l2, l3};
  };

  int kk = z * stepsPerZ * 32;
  issueW(kk);  // prologue
  for (int s = 0; s < stepsPerZ; ++s, kk += 32) {
    issueA(kk);   // async -> LDS; drained by compiler's vmcnt(0) at barrier1
    stageW();     // waits only on rw (landed during previous MFMA region)
    __syncthreads();                         // barrier1
    if (s + 1 < stepsPerZ) issueW(kk + 32);  // flies across barrier2 (T14)
#pragma unroll
    for (int ks = 0; ks < 2; ++ks) {
      bf16x8 ah[2], al[2], wh[2], wl[2];
#pragma unroll
      for (int i = 0; i < 2; ++i) {
        const int off = ((ks * 2 + khalf) * 128 + wm * 64 + i * 32 + l31) * 8;
        ah[i] = *(const bf16x8*)&sAh[off];
        al[i] = *(const bf16x8*)&sAl[off];
      }
#pragma unroll
      for (int j = 0; j < 2; ++j) {
        const int off = ((ks * 2 + khalf) * 128 + wn * 64 + j * 32 + l31) * 8;
        wh[j] = *(const bf16x8*)&sWh[off];
        wl[j] = *(const bf16x8*)&sWl[off];
      }
#pragma unroll
      for (int i = 0; i < 2; ++i)
#pragma unroll
        for (int j = 0; j < 2; ++j) {
          acc[i][j] = __builtin_amdgcn_mfma_f32_32x32x16_bf16(ah[i], wh[j], acc[i][j], 0, 0, 0);
          acc[i][j] = __builtin_amdgcn_mfma_f32_32x32x16_bf16(ah[i], wl[j], acc[i][j], 0, 0, 0);
          acc[i][j] = __builtin_amdgcn_mfma_f32_32x32x16_bf16(al[i], wh[j], acc[i][j], 0, 0, 0);
        }
    }
    __syncthreads();                         // barrier2
  }
  // C/D layout (32x32): col = lane&31, row = (r&3) + 8*(r>>2) + 4*(lane>>5)
#pragma unroll
  for (int i = 0; i < 2; ++i)
#pragma unroll
    for (int j = 0; j < 2; ++j)
#pragma unroll
      for (int r = 0; r < 16; ++r) {
        const int m = m0 + wm * 64 + i * 32 + (r & 3) + 8 * (r >> 2) + 4 * khalf;
        const int n = n0 + wn * 64 + j * 32 + l31;
        P[((size_t)z * 256 + m) * 1536 + n] = acc[i][j][r];
      }
}

// ---------------------------------------------------------------------------
// Fused cx + kwta-x1. One block (1024 thr) per row of the big-GEMM output.
// All threads: 4-way-unrolled z-reduce of col 512+t (x1 preact). Threads<512
// additionally reduce col t, tanh, *Wc2 -> block-reduce -> cx. Then exact
// stable-argsort kwta on the 1024 x1 preacts; emit hi/lo bf16.
// ---------------------------------------------------------------------------
__global__ void cx_kwta1(
    const float* __restrict__ P, const float* __restrict__ b_c1,
    const float* __restrict__ Wc2, const float* __restrict__ b1,
    float* __restrict__ cx, short* __restrict__ xh, short* __restrict__ xl,
    int S) {
  __shared__ float sdata[1024];
  __shared__ float red[16];
  __shared__ float scx;
  const int row = blockIdx.x, t = threadIdx.x;
  const float* base = P + (size_t)row * 1536;
  const size_t zs = (size_t)256 * 1536;
  float v;
  {
    float a0 = 0.f, a1 = 0.f, a2 = 0.f, a3 = 0.f;
    for (int z = 0; z < S; z += 4) {
      a0 += base[(size_t)(z + 0) * zs + 512 + t];
      a1 += base[(size_t)(z + 1) * zs + 512 + t];
      a2 += base[(size_t)(z + 2) * zs + 512 + t];
      a3 += base[(size_t)(z + 3) * zs + 512 + t];
    }
    v = ((a0 + a1) + (a2 + a3)) + b1[t];
  }
  float ctx = 0.f;
  if (t < 512) {
    float a0 = 0.f, a1 = 0.f, a2 = 0.f, a3 = 0.f;
    for (int z = 0; z < S; z += 4) {
      a0 += base[(size_t)(z + 0) * zs + t];
      a1 += base[(size_t)(z + 1) * zs + t];
      a2 += base[(size_t)(z + 2) * zs + t];
      a3 += base[(size_t)(z + 3) * zs + t];
    }
    const float pre = ((a0 + a1) + (a2 + a3)) + b_c1[t];
    ctx = tanhf(pre) * Wc2[t];
  }
  sdata[t] = v;
#pragma unroll
  for (int off = 32; off; off >>= 1) ctx += __shfl_down(ctx, off, 64);
  if ((t & 63) == 0) red[t >> 6] = ctx;
  __syncthreads();
  if (t == 0) {
    float s = 0.f;
#pragma unroll
    for (int i = 0; i < 8; ++i) s += red[i];
    const float c = 1.f / (1.f + expf(-s));
    scx = c;
    cx[row] = c;
  }
  __syncthreads();
  const int k = (int)(scx * 1024.f);  // trunc, matches .astype(int32)
  int cnt = 0;
  const float4* s4 = (const float4*)sdata;
  for (int i4 = 0; i4 < 256; ++i4) {
    const float4 s = s4[i4];
    const int b = i4 << 2;
    cnt += (s.x > v || (s.x == v && b < t));
    cnt += (s.y > v || (s.y == v && b + 1 < t));
    cnt += (s.z > v || (s.z == v && b + 2 < t));
    cnt += (s.w > v || (s.w == v && b + 3 < t));
  }
  const float o = (cnt < k) ? v : 0.f;
  const unsigned u = __float_as_uint(o);
  xh[(size_t)row * 1024 + t] = (short)(unsigned short)(u >> 16);
  const float rr = o - __uint_as_float(u & 0xffff0000u);
  xl[(size_t)row * 1024 + t] = (short)(unsigned short)(__float_as_uint(rr) >> 16);
}

// ---------------------------------------------------------------------------
// Fused: split-K reduce (4-way unrolled) + bias -> kwta -> emit hi/lo bf16.
// One block per row, n threads. S divisible by 4.
// ---------------------------------------------------------------------------
__global__ void kwta_fused(
    const float* __restrict__ P, int ldP, int S,
    const float* __restrict__ bias, const float* __restrict__ cx,
    short* __restrict__ xh, short* __restrict__ xl, int n) {
  extern __shared__ float sdata[];
  const int row = blockIdx.x, j = threadIdx.x;
  const float* base = P + (size_t)row * ldP + j;
  const size_t zs = (size_t)256 * ldP;
  float a0 = 0.f, a1 = 0.f, a2 = 0.f, a3 = 0.f;
  for (int z = 0; z < S; z += 4) {
    a0 += base[(size_t)(z + 0) * zs];
    a1 += base[(size_t)(z + 1) * zs];
    a2 += base[(size_t)(z + 2) * zs];
    a3 += base[(size_t)(z + 3) * zs];
  }
  const float v = ((a0 + a1) + (a2 + a3)) + bias[j];
  sdata[j] = v;
  __syncthreads();
  const int k = (int)(cx[row] * (float)n);  // trunc, matches .astype(int32)
  int cnt = 0;
  const float4* s4 = (const float4*)sdata;
  for (int i4 = 0; i4 < (n >> 2); ++i4) {
    const float4 s = s4[i4];
    const int b = i4 << 2;
    cnt += (s.x > v || (s.x == v && b < j));
    cnt += (s.y > v || (s.y == v && b + 1 < j));
    cnt += (s.z > v || (s.z == v && b + 2 < j));
    cnt += (s.w > v || (s.w == v && b + 3 < j));
  }
  const float o = (cnt < k) ? v : 0.f;
  const unsigned u = __float_as_uint(o);
  xh[(size_t)row * n + j] = (short)(unsigned short)(u >> 16);
  const float rr = o - __uint_as_float(u & 0xffff0000u);
  xl[(size_t)row * n + j] = (short)(unsigned short)(__float_as_uint(rr) >> 16);
}

// ---------------------------------------------------------------------------
// Small GEMM, pre-split bf16 operands, 3-term 16x16x32 MFMA. Block 64x64,
// 4 waves (wave = 16 rows x 64 cols), split-K partials. T14 reg-prefetch:
// next step's 4 global loads issue before barrier1, land under MFMA; only
// the prologue load is latency-exposed.
// ---------------------------------------------------------------------------
__global__ __launch_bounds__(256, 4) void gemm_sk(
    const short* __restrict__ Xh, const short* __restrict__ Xl,
    const short* __restrict__ Wh, const short* __restrict__ Wl,
    float* __restrict__ P, int N, int K, int stepsPerZ) {
  __shared__ short sXh[64 * 40], sXl[64 * 40], sWh[64 * 40], sWl[64 * 40];
  const int tid = threadIdx.x;
  const int n0 = blockIdx.x * 64, m0 = blockIdx.y * 64, z = blockIdx.z;
  const int lane = tid & 63, w = tid >> 6;
  const int l15 = lane & 15, q = lane >> 4;
  const int srow = tid >> 2, schunk = tid & 3;

  f32x4 acc[4];
#pragma unroll
  for (int j = 0; j < 4; ++j) acc[j] = (f32x4){0.f, 0.f, 0.f, 0.f};

  const short* pXh = Xh + (size_t)(m0 + srow) * K + schunk * 8;
  const short* pXl = Xl + (size_t)(m0 + srow) * K + schunk * 8;
  const short* pWh = Wh + (size_t)(n0 + srow) * K + schunk * 8;
  const short* pWl = Wl + (size_t)(n0 + srow) * K + schunk * 8;
  short* dXh = &sXh[srow * 40 + schunk * 8];
  short* dXl = &sXl[srow * 40 + schunk * 8];
  short* dWh = &sWh[srow * 40 + schunk * 8];
  short* dWl = &sWl[srow * 40 + schunk * 8];

  int kk = z * stepsPerZ * 32;
  bf16x8 rXh = *(const bf16x8*)(pXh + kk);
  bf16x8 rXl = *(const bf16x8*)(pXl + kk);
  bf16x8 rWh = *(const bf16x8*)(pWh + kk);
  bf16x8 rWl = *(const bf16x8*)(pWl + kk);
  for (int s = 0; s < stepsPerZ; ++s, kk += 32) {
    *(bf16x8*)dXh = rXh;
    *(bf16x8*)dXl = rXl;
    *(bf16x8*)dWh = rWh;
    *(bf16x8*)dWl = rWl;
    if (s + 1 < stepsPerZ) {  // issue next loads; land under this step's MFMA
      rXh = *(const bf16x8*)(pXh + kk + 32);
      rXl = *(const bf16x8*)(pXl + kk + 32);
      rWh = *(const bf16x8*)(pWh + kk + 32);
      rWl = *(const bf16x8*)(pWl + kk + 32);
    }
    __syncthreads();
    const int aoff = (w * 16 + l15) * 40 + q * 8;
    const bf16x8 ah = *(const bf16x8*)&sXh[aoff];
    const bf16x8 al = *(const bf16x8*)&sXl[aoff];
#pragma unroll
    for (int j = 0; j < 4; ++j) {
      const int woff = (j * 16 + l15) * 40 + q * 8;
      const bf16x8 whf = *(const bf16x8*)&sWh[woff];
      const bf16x8 wlf = *(const bf16x8*)&sWl[woff];
      acc[j] = __builtin_amdgcn_mfma_f32_16x16x32_bf16(ah, whf, acc[j], 0, 0, 0);
      acc[j] = __builtin_amdgcn_mfma_f32_16x16x32_bf16(ah, wlf, acc[j], 0, 0, 0);
      acc[j] = __builtin_amdgcn_mfma_f32_16x16x32_bf16(al, whf, acc[j], 0, 0, 0);
    }
    __syncthreads();
  }
  // C/D (16x16): col = lane&15, row = (lane>>4)*4 + r
#pragma unroll
  for (int j = 0; j < 4; ++j)
#pragma unroll
    for (int r = 0; r < 4; ++r) {
      const int m = m0 + w * 16 + q * 4 + r;
      const int n = n0 + j * 16 + l15;
      P[((size_t)z * 256 + m) * N + n] = acc[j][r];
    }
}

__global__ __launch_bounds__(256) void reduce_out(
    const float* __restrict__ P, float* __restrict__ out, int S) {
  const int idx = blockIdx.x * 256 + threadIdx.x;
  float a0 = 0.f, a1 = 0.f, a2 = 0.f, a3 = 0.f;
  for (int z = 0; z < S; z += 4) {
    a0 += P[(size_t)(z + 0) * 262144 + idx];
    a1 += P[(size_t)(z + 1) * 262144 + idx];
    a2 += P[(size_t)(z + 2) * 262144 + idx];
    a3 += P[(size_t)(z + 3) * 262144 + idx];
  }
  out[idx] = (a0 + a1) + (a2 + a3);
}

extern "C" void kernel_launch(void* const* d_in, const int* in_sizes, int n_in,
                              void* d_out, int out_size, void* d_ws, size_t ws_size,
                              hipStream_t stream) {
  const float* input = (const float*)d_in[0];
  const float* W_c1  = (const float*)d_in[1];
  const float* b_c1  = (const float*)d_in[2];
  const float* W_c2  = (const float*)d_in[3];
  const float* W1    = (const float*)d_in[4];
  const float* b1    = (const float*)d_in[5];
  const float* W2    = (const float*)d_in[6];
  const float* b2    = (const float*)d_in[7];
  const float* W3    = (const float*)d_in[8];
  const float* b3    = (const float*)d_in[9];
  const float* W4    = (const float*)d_in[10];
  float* out = (float*)d_out;

  char* wsb = (char*)d_ws;
  size_t off = 0;
  auto alloc = [&](size_t bytes) {
    char* p = wsb + off;
    off += (bytes + 255) & ~(size_t)255;
    return p;
  };
  float* cx  = (float*)alloc(1024);
  short* x1h = (short*)alloc(524288);  short* x1l = (short*)alloc(524288);
  short* x2h = (short*)alloc(262144);  short* x2l = (short*)alloc(262144);
  short* x3h = (short*)alloc(524288);  short* x3l = (short*)alloc(524288);
  short* W2h = (short*)alloc(1048576); short* W2l = (short*)alloc(1048576);
  short* W3h = (short*)alloc(1048576); short* W3l = (short*)alloc(1048576);
  short* W4h = (short*)alloc(2097152); short* W4l = (short*)alloc(2097152);
  short* Ahg = (short*)alloc(16777216); short* Alg = (short*)alloc(16777216);
  // Split-K partial buffer (big GEMM: S*256*1536 fp32; small GEMMs reuse <=8 MB)
  int S_big = 32;
  while (S_big > 8 && off + (size_t)S_big * 1572864ull > ws_size) S_big >>= 1;
  float* P = (float*)(wsb + off);
  const int stepsBig = 1024 / S_big;  // K-32 steps per z-chunk

  // 1. merged pre-split (A blocked layout + W2/W3/W4)
  presplit_aw<<<2048, 256, 0, stream>>>(input, Ahg, Alg, W2, W3, W4,
                                        W2h, W2l, W3h, W3l, W4h, W4l);
  // 2. big fused GEMM -> P  (1D grid, XCD-aware decode inside; 24 blocks/z)
  big_gemm6<<<24 * S_big, 256, 0, stream>>>(Ahg, Alg, W_c1, W1, P, stepsBig);
  // 3. fused cx + kwta x1 -> cx, x1h/x1l
  cx_kwta1<<<256, 1024, 0, stream>>>(P, b_c1, W_c2, b1, cx, x1h, x1l, S_big);
  // 4. x2 = x1 @ W2^T : K=1024, N=512, S=16 (512 blocks = 2/CU)
  {
    dim3 g(8, 4, 16);
    gemm_sk<<<g, 256, 0, stream>>>(x1h, x1l, W2h, W2l, P, 512, 1024, 2);
  }
  // 5. kwta x2 (+b2) -> x2h/x2l
  kwta_fused<<<256, 512, 512 * 4, stream>>>(P, 512, 16, b2, cx, x2h, x2l, 512);
  // 6. x3 = x2 @ W3^T : K=512, N=1024, S=8
  {
    dim3 g(16, 4, 8);
    gemm_sk<<<g, 256, 0, stream>>>(x2h, x2l, W3h, W3l, P, 1024, 512, 2);
  }
  // 7. kwta x3 (+b3) -> x3h/x3l
  kwta_fused<<<256, 1024, 1024 * 4, stream>>>(P, 1024, 8, b3, cx, x3h, x3l, 1024);
  // 8. out = x3 @ W4^T : K=1024, N=1024, S=8
  {
    dim3 g(16, 4, 8);
    gemm_sk<<<g, 256, 0, stream>>>(x3h, x3l, W4h, W4l, P, 1024, 1024, 4);
  }
  // 9. final reduce
  reduce_out<<<1024, 256, 0, stream>>>(P, out, 8);
}